// Round 1
// baseline (894.525 us; speedup 1.0000x reference)
//
#include <hip/hip_runtime.h>

#define NN   100000
#define E0   1600000
#define ET   1700000
#define NEG  0.2f
#define EPSV 1e-16f

// order-preserving float->uint encoding for atomicMax; 0u == minimum
__device__ __forceinline__ unsigned enc_f(float f) {
    unsigned u = __float_as_uint(f);
    return (u & 0x80000000u) ? ~u : (u | 0x80000000u);
}
__device__ __forceinline__ float dec_f(unsigned u) {
    unsigned b = (u & 0x80000000u) ? (u ^ 0x80000000u) : ~u;
    return __uint_as_float(b);
}

// ---- Layer 1: h1 = x @ W1 (64x64), plus per-node a_src/a_dst logits ----
__global__ __launch_bounds__(256) void k_gemm1(
    const float* __restrict__ x, const float* __restrict__ W1,
    const float* __restrict__ as1, const float* __restrict__ ad1,
    float* __restrict__ h1, float* __restrict__ asrc1, float* __restrict__ adst1)
{
    __shared__ float Wl[64 * 64];
    __shared__ float xs[4][64];
    int tid = threadIdx.x;
    for (int i = tid; i < 4096; i += 256) Wl[i] = W1[i];
    int w = tid >> 6, lane = tid & 63;
    int n = blockIdx.x * 4 + w;
    xs[w][lane] = x[n * 64 + lane];
    __syncthreads();
    float acc = 0.f;
#pragma unroll
    for (int k = 0; k < 64; ++k) acc += xs[w][k] * Wl[k * 64 + lane];
    h1[n * 64 + lane] = acc;
    int hh = lane >> 4, cc = lane & 15;
    float av = acc * as1[hh * 16 + cc];
    float dv = acc * ad1[hh * 16 + cc];
#pragma unroll
    for (int off = 8; off; off >>= 1) {
        av += __shfl_down(av, off, 16);
        dv += __shfl_down(dv, off, 16);
    }
    if (cc == 0) { asrc1[n * 4 + hh] = av; adst1[n * 4 + hh] = dv; }
}

// ---- Layer 1 edge pass 1: segment max per (dst, head) ----
__global__ __launch_bounds__(256) void k_e1max(
    const int* __restrict__ ei, const float* __restrict__ asrc1,
    const float* __restrict__ adst1, unsigned* __restrict__ m1)
{
    int idx = blockIdx.x * 256 + threadIdx.x;
    if (idx >= ET * 4) return;
    int e = idx >> 2, hh = idx & 3;
    int s, d;
    if (e < E0) { s = ei[e]; d = ei[E0 + e]; } else { s = d = e - E0; }
    float a = asrc1[s * 4 + hh] + adst1[d * 4 + hh];
    a = a > 0.f ? a : NEG * a;
    atomicMax(&m1[d * 4 + hh], enc_f(a));
}

// ---- Layer 1 edge pass 2: fused exp/denominator/message accumulation ----
// one wave (64 lanes) per edge; lane = head*16 + channel
__global__ __launch_bounds__(256) void k_e1msg(
    const int* __restrict__ ei, const float* __restrict__ asrc1,
    const float* __restrict__ adst1, const unsigned* __restrict__ m1,
    const float* __restrict__ h1, float* __restrict__ outr, float* __restrict__ den)
{
    int idx = blockIdx.x * 256 + threadIdx.x;   // < ET*64 = 108.8M
    int e = idx >> 6, lane = idx & 63, hh = lane >> 4;
    int s, d;
    if (e < E0) { s = ei[e]; d = ei[E0 + e]; } else { s = d = e - E0; }
    float a = asrc1[s * 4 + hh] + adst1[d * 4 + hh];
    a = a > 0.f ? a : NEG * a;
    float ev = expf(a - dec_f(m1[d * 4 + hh]));
    atomicAdd(&outr[d * 64 + lane], ev * h1[s * 64 + lane]);
    if ((lane & 15) == 0) atomicAdd(&den[d * 4 + hh], ev);
}

// ---- Layer 1 finalize (+b1, ELU) fused with layer-2 projection g = h2 @ W2 ----
__global__ __launch_bounds__(256) void k_n1fin(
    const float* __restrict__ outr, const float* __restrict__ den,
    const float* __restrict__ b1, const float* __restrict__ W2,
    const float* __restrict__ att_s2, const float* __restrict__ att_d2,
    float* __restrict__ g, float* __restrict__ asrc2, float* __restrict__ adst2)
{
    int tid = threadIdx.x;
    int w = tid >> 6, lane = tid & 63;
    int n = blockIdx.x * 4 + w;
    float v = outr[n * 64 + lane] / (den[n * 4 + (lane >> 4)] + EPSV) + b1[lane];
    v = v > 0.f ? v : expf(v) - 1.f;   // ELU(alpha=1)
    float gv = v * W2[lane];
#pragma unroll
    for (int off = 32; off; off >>= 1) gv += __shfl_down(gv, off, 64);
    if (lane == 0) {
        g[n] = gv;
        asrc2[n] = gv * att_s2[0];
        adst2[n] = gv * att_d2[0];
    }
}

// ---- Layer 2 edge pass 1: segment max (1 head) ----
__global__ __launch_bounds__(256) void k_e2max(
    const int* __restrict__ ei, const float* __restrict__ asrc2,
    const float* __restrict__ adst2, unsigned* __restrict__ m2)
{
    int idx = blockIdx.x * 256 + threadIdx.x;
    if (idx >= ET) return;
    int s, d;
    if (idx < E0) { s = ei[idx]; d = ei[E0 + idx]; } else { s = d = idx - E0; }
    float a = asrc2[s] + adst2[d];
    a = a > 0.f ? a : NEG * a;
    atomicMax(&m2[d], enc_f(a));
}

// ---- Layer 2 edge pass 2: fused denom + message ----
__global__ __launch_bounds__(256) void k_e2msg(
    const int* __restrict__ ei, const float* __restrict__ asrc2,
    const float* __restrict__ adst2, const unsigned* __restrict__ m2,
    const float* __restrict__ g, float* __restrict__ outr2, float* __restrict__ den2)
{
    int idx = blockIdx.x * 256 + threadIdx.x;
    if (idx >= ET) return;
    int s, d;
    if (idx < E0) { s = ei[idx]; d = ei[E0 + idx]; } else { s = d = idx - E0; }
    float a = asrc2[s] + adst2[d];
    a = a > 0.f ? a : NEG * a;
    float ev = expf(a - dec_f(m2[d]));
    atomicAdd(&den2[d], ev);
    atomicAdd(&outr2[d], ev * g[s]);
}

// ---- Layer 2 finalize ----
__global__ __launch_bounds__(256) void k_out(
    const float* __restrict__ outr2, const float* __restrict__ den2,
    const float* __restrict__ b2, float* __restrict__ out)
{
    int n = blockIdx.x * 256 + threadIdx.x;
    if (n < NN) out[n] = outr2[n] / (den2[n] + EPSV) + b2[0];
}

extern "C" void kernel_launch(void* const* d_in, const int* in_sizes, int n_in,
                              void* d_out, int out_size, void* d_ws, size_t ws_size,
                              hipStream_t stream)
{
    const float* x   = (const float*)d_in[0];
    const int*   ei  = (const int*)d_in[1];
    const float* W1  = (const float*)d_in[2];
    const float* as1 = (const float*)d_in[3];
    const float* ad1 = (const float*)d_in[4];
    const float* b1  = (const float*)d_in[5];
    const float* W2  = (const float*)d_in[6];
    const float* as2 = (const float*)d_in[7];
    const float* ad2 = (const float*)d_in[8];
    const float* b2  = (const float*)d_in[9];
    float* out = (float*)d_out;

    // workspace layout (floats)
    float* ws = (float*)d_ws;
    float*    h1    = ws;                         // 6,400,000
    float*    asrc1 = ws + 6400000;               //   400,000
    float*    adst1 = ws + 6800000;               //   400,000
    float*    g     = ws + 7200000;               //   100,000
    float*    asrc2 = ws + 7300000;               //   100,000
    float*    adst2 = ws + 7400000;               //   100,000
    // ---- zero-init region starts here (m encodings: 0u == -inf) ----
    unsigned* m1    = (unsigned*)(ws + 7500000);  //   400,000
    float*    den1  = ws + 7900000;               //   400,000
    float*    outr1 = ws + 8300000;               // 6,400,000
    unsigned* m2    = (unsigned*)(ws + 14700000); //   100,000
    float*    den2  = ws + 14800000;              //   100,000
    float*    outr2 = ws + 14900000;              //   100,000
    // total: 15,000,000 floats = 60 MB

    hipMemsetAsync(ws + 7500000, 0, (size_t)7500000 * sizeof(float), stream);

    k_gemm1<<<NN / 4, 256, 0, stream>>>(x, W1, as1, ad1, h1, asrc1, adst1);
    k_e1max<<<(ET * 4 + 255) / 256, 256, 0, stream>>>(ei, asrc1, adst1, m1);
    k_e1msg<<<ET / 4, 256, 0, stream>>>(ei, asrc1, adst1, m1, h1, outr1, den1);
    k_n1fin<<<NN / 4, 256, 0, stream>>>(outr1, den1, b1, W2, as2, ad2, g, asrc2, adst2);
    k_e2max<<<(ET + 255) / 256, 256, 0, stream>>>(ei, asrc2, adst2, m2);
    k_e2msg<<<(ET + 255) / 256, 256, 0, stream>>>(ei, asrc2, adst2, m2, g, outr2, den2);
    k_out<<<(NN + 255) / 256, 256, 0, stream>>>(outr2, den2, b2, out);
}

// Round 2
// 758.646 us; speedup vs baseline: 1.1791x; 1.1791x over previous
//
#include <hip/hip_runtime.h>
#include <hip/hip_fp16.h>

#define NN   100000
#define E0   1600000
#define ET   1700000
#define NEG  0.2f
#define EPSV 1e-16f

// ---- CSR build step 1: per-dst degree histogram (self-loops included) ----
__global__ __launch_bounds__(256) void k_hist(const int* __restrict__ ei, int* __restrict__ deg)
{
    int idx = blockIdx.x * 256 + threadIdx.x;
    if (idx >= ET) return;
    int d = (idx < E0) ? ei[E0 + idx] : (idx - E0);
    atomicAdd(&deg[d], 1);
}

// ---- CSR build step 2: exclusive scan (single 1024-thread block) ----
__global__ __launch_bounds__(1024) void k_scan(const int* __restrict__ deg,
                                               int* __restrict__ rowptr, int* __restrict__ cursor)
{
    __shared__ int sums[1024];
    int t = threadIdx.x;
    int begin = t * 98;
    int end = begin + 98; if (end > NN) end = NN; if (begin > NN) begin = NN;
    int s = 0;
    for (int i = begin; i < end; ++i) s += deg[i];
    sums[t] = s;
    __syncthreads();
    for (int off = 1; off < 1024; off <<= 1) {
        int v = (t >= off) ? sums[t - off] : 0;
        __syncthreads();
        sums[t] += v;
        __syncthreads();
    }
    int excl = (t == 0) ? 0 : sums[t - 1];
    for (int i = begin; i < end; ++i) {
        rowptr[i] = excl; cursor[i] = excl; excl += deg[i];
    }
    if (t == 1023) rowptr[NN] = sums[1023];
}

// ---- CSR build step 3: scatter src ids into dst-grouped order ----
__global__ __launch_bounds__(256) void k_scatter(const int* __restrict__ ei,
                                                 int* __restrict__ cursor, int* __restrict__ csr)
{
    int idx = blockIdx.x * 256 + threadIdx.x;
    if (idx >= ET) return;
    int s, d;
    if (idx < E0) { s = ei[idx]; d = ei[E0 + idx]; } else { s = d = idx - E0; }
    int pos = atomicAdd(&cursor[d], 1);
    csr[pos] = s;
}

// ---- Layer 1: h1 = x @ W1 (64x64) -> fp16, plus per-node logits ----
__global__ __launch_bounds__(256) void k_gemm1(
    const float* __restrict__ x, const float* __restrict__ W1,
    const float* __restrict__ as1, const float* __restrict__ ad1,
    __half* __restrict__ h1h, float* __restrict__ asrc1, float* __restrict__ adst1)
{
    __shared__ float Wl[64 * 64];
    __shared__ float xs[4][64];
    int tid = threadIdx.x;
    for (int i = tid; i < 4096; i += 256) Wl[i] = W1[i];
    int w = tid >> 6, lane = tid & 63;
    int n = blockIdx.x * 4 + w;
    xs[w][lane] = x[n * 64 + lane];
    __syncthreads();
    float acc = 0.f;
#pragma unroll
    for (int k = 0; k < 64; ++k) acc += xs[w][k] * Wl[k * 64 + lane];
    h1h[n * 64 + lane] = __float2half(acc);
    int hh = lane >> 4, cc = lane & 15;
    float av = acc * as1[hh * 16 + cc];
    float dv = acc * ad1[hh * 16 + cc];
#pragma unroll
    for (int off = 8; off; off >>= 1) {
        av += __shfl_down(av, off, 16);
        dv += __shfl_down(dv, off, 16);
    }
    if (cc == 0) { asrc1[n * 4 + hh] = av; adst1[n * 4 + hh] = dv; }
}

// ---- Layer 1 aggregation: one wave per dst node, register accumulation.
// No segment-max needed: |alpha| small, softmax is shift-invariant.
// Fused finalize: bias, ELU, W2 projection, layer-2 logits.
__global__ __launch_bounds__(256) void k_e1agg(
    const int* __restrict__ rowptr, const int* __restrict__ csr,
    const float* __restrict__ asrc1, const float* __restrict__ adst1,
    const __half* __restrict__ h1h, const float* __restrict__ b1,
    const float* __restrict__ W2, const float* __restrict__ att_s2,
    const float* __restrict__ att_d2,
    float* __restrict__ g, float* __restrict__ asrc2, float* __restrict__ adst2)
{
    int w = threadIdx.x >> 6, lane = threadIdx.x & 63;
    int n = blockIdx.x * 4 + w;
    int hh = lane >> 4;
    float ad = adst1[n * 4 + hh];
    int beg = rowptr[n], end = rowptr[n + 1];
    float acc = 0.f, den = 0.f;
    for (int j = beg; j < end; ++j) {
        int s = csr[j];
        float a = asrc1[s * 4 + hh] + ad;
        a = a > 0.f ? a : NEG * a;
        float ev = __expf(a);
        den += ev;
        acc += ev * __half2float(h1h[s * 64 + lane]);
    }
    float v = acc / (den + EPSV) + b1[lane];
    v = v > 0.f ? v : expf(v) - 1.f;            // ELU
    float gv = v * W2[lane];
#pragma unroll
    for (int off = 32; off; off >>= 1) gv += __shfl_down(gv, off, 64);
    if (lane == 0) {
        g[n] = gv;
        asrc2[n] = gv * att_s2[0];
        adst2[n] = gv * att_d2[0];
    }
}

// ---- Layer 2 aggregation: one thread per dst node (scalar head) ----
__global__ __launch_bounds__(256) void k_e2agg(
    const int* __restrict__ rowptr, const int* __restrict__ csr,
    const float* __restrict__ asrc2, const float* __restrict__ adst2,
    const float* __restrict__ g, const float* __restrict__ b2,
    float* __restrict__ out)
{
    int n = blockIdx.x * 256 + threadIdx.x;
    if (n >= NN) return;
    float ad = adst2[n];
    int beg = rowptr[n], end = rowptr[n + 1];
    float acc = 0.f, den = 0.f;
    for (int j = beg; j < end; ++j) {
        int s = csr[j];
        float a = asrc2[s] + ad;
        a = a > 0.f ? a : NEG * a;
        float ev = __expf(a);
        den += ev;
        acc += ev * g[s];
    }
    out[n] = acc / (den + EPSV) + b2[0];
}

extern "C" void kernel_launch(void* const* d_in, const int* in_sizes, int n_in,
                              void* d_out, int out_size, void* d_ws, size_t ws_size,
                              hipStream_t stream)
{
    const float* x   = (const float*)d_in[0];
    const int*   ei  = (const int*)d_in[1];
    const float* W1  = (const float*)d_in[2];
    const float* as1 = (const float*)d_in[3];
    const float* ad1 = (const float*)d_in[4];
    const float* b1  = (const float*)d_in[5];
    const float* W2  = (const float*)d_in[6];
    const float* as2 = (const float*)d_in[7];
    const float* ad2 = (const float*)d_in[8];
    const float* b2  = (const float*)d_in[9];
    float* out = (float*)d_out;

    // workspace layout (units of 4 bytes from base)
    int*   iw     = (int*)d_ws;
    float* fw     = (float*)d_ws;
    int*   deg    = iw;                 // 100,000
    int*   rowptr = iw + 100000;        // 100,001
    int*   cursor = iw + 200008;        // 100,000
    int*   csr    = iw + 300008;        // 1,700,000
    float* asrc1  = fw + 2000008;       //   400,000
    float* adst1  = fw + 2400008;       //   400,000
    float* g      = fw + 2800008;       //   100,000
    float* asrc2  = fw + 2900008;       //   100,000
    float* adst2  = fw + 3000008;       //   100,000
    __half* h1h   = (__half*)(fw + 3100008); // 6,400,000 halves = 3.2M slots
    // total ~6.3M slots = 25.2 MB

    hipMemsetAsync(deg, 0, (size_t)NN * sizeof(int), stream);

    k_hist   <<<(ET + 255) / 256, 256, 0, stream>>>(ei, deg);
    k_scan   <<<1, 1024, 0, stream>>>(deg, rowptr, cursor);
    k_scatter<<<(ET + 255) / 256, 256, 0, stream>>>(ei, cursor, csr);
    k_gemm1  <<<NN / 4, 256, 0, stream>>>(x, W1, as1, ad1, h1h, asrc1, adst1);
    k_e1agg  <<<NN / 4, 256, 0, stream>>>(rowptr, csr, asrc1, adst1, h1h, b1, W2, as2, ad2,
                                          g, asrc2, adst2);
    k_e2agg  <<<(NN + 255) / 256, 256, 0, stream>>>(rowptr, csr, asrc2, adst2, g, b2, out);
}

// Round 3
// 533.405 us; speedup vs baseline: 1.6770x; 1.4223x over previous
//
#include <hip/hip_runtime.h>
#include <hip/hip_fp16.h>

#define NN   100000
#define E0   1600000
#define ET   1700000
#define NEG  0.2f
#define EPSV 1e-16f
#define NCHUNK 391   // ceil(NN/256)

// ---- CSR build step 1: per-dst degree histogram (self-loops included) ----
__global__ __launch_bounds__(256) void k_hist(const int* __restrict__ ei, int* __restrict__ deg)
{
    int idx = blockIdx.x * 256 + threadIdx.x;
    if (idx >= ET) return;
    int d = (idx < E0) ? ei[E0 + idx] : (idx - E0);
    atomicAdd(&deg[d], 1);
}

// ---- scan phase 1: per-block (256-elem) sums ----
__global__ __launch_bounds__(256) void k_s1(const int* __restrict__ deg, int* __restrict__ bsum)
{
    int i = blockIdx.x * 256 + threadIdx.x;
    int v = (i < NN) ? deg[i] : 0;
    int lane = threadIdx.x & 63, wid = threadIdx.x >> 6;
#pragma unroll
    for (int off = 32; off; off >>= 1) v += __shfl_down(v, off, 64);
    __shared__ int wsum[4];
    if (lane == 0) wsum[wid] = v;
    __syncthreads();
    if (threadIdx.x == 0) bsum[blockIdx.x] = wsum[0] + wsum[1] + wsum[2] + wsum[3];
}

// ---- scan phase 2: exclusive scan of 391 block sums (one block) ----
__global__ __launch_bounds__(512) void k_s2(const int* __restrict__ bsum, int* __restrict__ boff)
{
    int t = threadIdx.x;
    int v = (t < NCHUNK) ? bsum[t] : 0;
    int lane = t & 63, wid = t >> 6;
    int sc = v;
#pragma unroll
    for (int off = 1; off < 64; off <<= 1) {
        int u = __shfl_up(sc, off, 64);
        if (lane >= off) sc += u;
    }
    __shared__ int wsum[8];
    if (lane == 63) wsum[wid] = sc;
    __syncthreads();
    int woff = 0;
    for (int k = 0; k < wid; ++k) woff += wsum[k];
    if (t < NCHUNK) boff[t] = sc + woff - v;   // exclusive
}

// ---- scan phase 3: per-block local exclusive scan + global offset ----
__global__ __launch_bounds__(256) void k_s3(const int* __restrict__ deg, const int* __restrict__ boff,
                                            int* __restrict__ rowptr, int* __restrict__ cursor)
{
    int t = threadIdx.x;
    int i = blockIdx.x * 256 + t;
    int v = (i < NN) ? deg[i] : 0;
    int lane = t & 63, wid = t >> 6;
    int sc = v;
#pragma unroll
    for (int off = 1; off < 64; off <<= 1) {
        int u = __shfl_up(sc, off, 64);
        if (lane >= off) sc += u;
    }
    __shared__ int wsum[4];
    if (lane == 63) wsum[wid] = sc;
    __syncthreads();
    int woff = 0;
    for (int k = 0; k < wid; ++k) woff += wsum[k];
    int incl = sc + woff + boff[blockIdx.x];
    int excl = incl - v;
    if (i < NN) { rowptr[i] = excl; cursor[i] = excl; }
    if (i == NN - 1) rowptr[NN] = incl;
}

// ---- CSR build step 3: scatter src ids into dst-grouped order ----
__global__ __launch_bounds__(256) void k_scatter(const int* __restrict__ ei,
                                                 int* __restrict__ cursor, int* __restrict__ csr)
{
    int idx = blockIdx.x * 256 + threadIdx.x;
    if (idx >= ET) return;
    int s, d;
    if (idx < E0) { s = ei[idx]; d = ei[E0 + idx]; } else { s = d = idx - E0; }
    int pos = atomicAdd(&cursor[d], 1);
    csr[pos] = s;
}

// ---- Layer 1: h1 = x @ W1 (64x64) -> fp16, plus per-node logits ----
__global__ __launch_bounds__(256) void k_gemm1(
    const float* __restrict__ x, const float* __restrict__ W1,
    const float* __restrict__ as1, const float* __restrict__ ad1,
    __half* __restrict__ h1h, float* __restrict__ asrc1, float* __restrict__ adst1)
{
    __shared__ float Wl[64 * 64];
    __shared__ float xs[4][64];
    int tid = threadIdx.x;
    for (int i = tid; i < 4096; i += 256) Wl[i] = W1[i];
    int w = tid >> 6, lane = tid & 63;
    int n = blockIdx.x * 4 + w;
    xs[w][lane] = x[n * 64 + lane];
    __syncthreads();
    float acc = 0.f;
#pragma unroll
    for (int k = 0; k < 64; ++k) acc += xs[w][k] * Wl[k * 64 + lane];
    h1h[n * 64 + lane] = __float2half(acc);
    int hh = lane >> 4, cc = lane & 15;
    float av = acc * as1[hh * 16 + cc];
    float dv = acc * ad1[hh * 16 + cc];
#pragma unroll
    for (int off = 8; off; off >>= 1) {
        av += __shfl_down(av, off, 16);
        dv += __shfl_down(dv, off, 16);
    }
    if (cc == 0) { asrc1[n * 4 + hh] = av; adst1[n * 4 + hh] = dv; }
}

// ---- Layer 1 aggregation: one wave per dst node, register accumulation.
// No segment-max needed: |alpha| small, softmax is shift-invariant.
// Fused finalize: bias, ELU, W2 projection, layer-2 logits.
__global__ __launch_bounds__(256) void k_e1agg(
    const int* __restrict__ rowptr, const int* __restrict__ csr,
    const float* __restrict__ asrc1, const float* __restrict__ adst1,
    const __half* __restrict__ h1h, const float* __restrict__ b1,
    const float* __restrict__ W2, const float* __restrict__ att_s2,
    const float* __restrict__ att_d2,
    float* __restrict__ g, float* __restrict__ asrc2, float* __restrict__ adst2)
{
    int w = threadIdx.x >> 6, lane = threadIdx.x & 63;
    int n = blockIdx.x * 4 + w;
    int hh = lane >> 4;
    float ad = adst1[n * 4 + hh];
    int beg = rowptr[n], end = rowptr[n + 1];
    float acc = 0.f, den = 0.f;
    for (int j = beg; j < end; ++j) {
        int s = csr[j];
        float a = asrc1[s * 4 + hh] + ad;
        a = a > 0.f ? a : NEG * a;
        float ev = __expf(a);
        den += ev;
        acc += ev * __half2float(h1h[s * 64 + lane]);
    }
    float v = acc / (den + EPSV) + b1[lane];
    v = v > 0.f ? v : expf(v) - 1.f;            // ELU
    float gv = v * W2[lane];
#pragma unroll
    for (int off = 32; off; off >>= 1) gv += __shfl_down(gv, off, 64);
    if (lane == 0) {
        g[n] = gv;
        asrc2[n] = gv * att_s2[0];
        adst2[n] = gv * att_d2[0];
    }
}

// ---- Layer 2 aggregation: one thread per dst node (scalar head) ----
__global__ __launch_bounds__(256) void k_e2agg(
    const int* __restrict__ rowptr, const int* __restrict__ csr,
    const float* __restrict__ asrc2, const float* __restrict__ adst2,
    const float* __restrict__ g, const float* __restrict__ b2,
    float* __restrict__ out)
{
    int n = blockIdx.x * 256 + threadIdx.x;
    if (n >= NN) return;
    float ad = adst2[n];
    int beg = rowptr[n], end = rowptr[n + 1];
    float acc = 0.f, den = 0.f;
    for (int j = beg; j < end; ++j) {
        int s = csr[j];
        float a = asrc2[s] + ad;
        a = a > 0.f ? a : NEG * a;
        float ev = __expf(a);
        den += ev;
        acc += ev * g[s];
    }
    out[n] = acc / (den + EPSV) + b2[0];
}

extern "C" void kernel_launch(void* const* d_in, const int* in_sizes, int n_in,
                              void* d_out, int out_size, void* d_ws, size_t ws_size,
                              hipStream_t stream)
{
    const float* x   = (const float*)d_in[0];
    const int*   ei  = (const int*)d_in[1];
    const float* W1  = (const float*)d_in[2];
    const float* as1 = (const float*)d_in[3];
    const float* ad1 = (const float*)d_in[4];
    const float* b1  = (const float*)d_in[5];
    const float* W2  = (const float*)d_in[6];
    const float* as2 = (const float*)d_in[7];
    const float* ad2 = (const float*)d_in[8];
    const float* b2  = (const float*)d_in[9];
    float* out = (float*)d_out;

    // workspace layout (units of 4 bytes from base)
    int*   iw     = (int*)d_ws;
    float* fw     = (float*)d_ws;
    int*   deg    = iw;                 // 100,000
    int*   rowptr = iw + 100000;        // 100,001
    int*   cursor = iw + 200008;        // 100,000
    int*   csr    = iw + 300008;        // 1,700,000
    int*   bsum   = iw + 2000008;       //       391
    int*   boff   = iw + 2000400;       //       391
    float* asrc1  = fw + 2000800;       //   400,000
    float* adst1  = fw + 2400800;       //   400,000
    float* g      = fw + 2800800;       //   100,000
    float* asrc2  = fw + 2900800;       //   100,000
    float* adst2  = fw + 3000800;       //   100,000
    __half* h1h   = (__half*)(fw + 3100800); // 6,400,000 halves = 3.2M slots
    // total ~6.3M slots ≈ 25.2 MB

    hipMemsetAsync(deg, 0, (size_t)NN * sizeof(int), stream);

    k_hist   <<<(ET + 255) / 256, 256, 0, stream>>>(ei, deg);
    k_s1     <<<NCHUNK, 256, 0, stream>>>(deg, bsum);
    k_s2     <<<1, 512, 0, stream>>>(bsum, boff);
    k_s3     <<<NCHUNK, 256, 0, stream>>>(deg, boff, rowptr, cursor);
    k_scatter<<<(ET + 255) / 256, 256, 0, stream>>>(ei, cursor, csr);
    k_gemm1  <<<NN / 4, 256, 0, stream>>>(x, W1, as1, ad1, h1h, asrc1, adst1);
    k_e1agg  <<<NN / 4, 256, 0, stream>>>(rowptr, csr, asrc1, adst1, h1h, b1, W2, as2, ad2,
                                          g, asrc2, adst2);
    k_e2agg  <<<(NN + 255) / 256, 256, 0, stream>>>(rowptr, csr, asrc2, adst2, g, b2, out);
}

// Round 4
// 447.153 us; speedup vs baseline: 2.0005x; 1.1929x over previous
//
#include <hip/hip_runtime.h>
#include <hip/hip_fp16.h>

#define NN   100000
#define E0   1600000
#define ET   1700000
#define NEG  0.2f
#define EPSV 1e-16f
#define NCHUNK 391   // ceil(NN/256)

// ---- CSR build step 1: per-dst degree histogram (self-loops included) ----
__global__ __launch_bounds__(256) void k_hist(const int* __restrict__ ei, int* __restrict__ deg)
{
    int idx = blockIdx.x * 256 + threadIdx.x;
    if (idx >= ET) return;
    int d = (idx < E0) ? ei[E0 + idx] : (idx - E0);
    atomicAdd(&deg[d], 1);
}

// ---- scan phase 1: per-block (256-elem) sums ----
__global__ __launch_bounds__(256) void k_s1(const int* __restrict__ deg, int* __restrict__ bsum)
{
    int i = blockIdx.x * 256 + threadIdx.x;
    int v = (i < NN) ? deg[i] : 0;
    int lane = threadIdx.x & 63, wid = threadIdx.x >> 6;
#pragma unroll
    for (int off = 32; off; off >>= 1) v += __shfl_down(v, off, 64);
    __shared__ int wsum[4];
    if (lane == 0) wsum[wid] = v;
    __syncthreads();
    if (threadIdx.x == 0) bsum[blockIdx.x] = wsum[0] + wsum[1] + wsum[2] + wsum[3];
}

// ---- scan phase 2: exclusive scan of 391 block sums (one block) ----
__global__ __launch_bounds__(512) void k_s2(const int* __restrict__ bsum, int* __restrict__ boff)
{
    int t = threadIdx.x;
    int v = (t < NCHUNK) ? bsum[t] : 0;
    int lane = t & 63, wid = t >> 6;
    int sc = v;
#pragma unroll
    for (int off = 1; off < 64; off <<= 1) {
        int u = __shfl_up(sc, off, 64);
        if (lane >= off) sc += u;
    }
    __shared__ int wsum[8];
    if (lane == 63) wsum[wid] = sc;
    __syncthreads();
    int woff = 0;
    for (int k = 0; k < wid; ++k) woff += wsum[k];
    if (t < NCHUNK) boff[t] = sc + woff - v;   // exclusive
}

// ---- scan phase 3: per-block local exclusive scan + global offset ----
__global__ __launch_bounds__(256) void k_s3(const int* __restrict__ deg, const int* __restrict__ boff,
                                            int* __restrict__ rowptr, int* __restrict__ cursor)
{
    int t = threadIdx.x;
    int i = blockIdx.x * 256 + t;
    int v = (i < NN) ? deg[i] : 0;
    int lane = t & 63, wid = t >> 6;
    int sc = v;
#pragma unroll
    for (int off = 1; off < 64; off <<= 1) {
        int u = __shfl_up(sc, off, 64);
        if (lane >= off) sc += u;
    }
    __shared__ int wsum[4];
    if (lane == 63) wsum[wid] = sc;
    __syncthreads();
    int woff = 0;
    for (int k = 0; k < wid; ++k) woff += wsum[k];
    int incl = sc + woff + boff[blockIdx.x];
    int excl = incl - v;
    if (i < NN) { rowptr[i] = excl; cursor[i] = excl; }
    if (i == NN - 1) rowptr[NN] = incl;
}

// ---- CSR build step 3: scatter src ids into dst-grouped order ----
__global__ __launch_bounds__(256) void k_scatter(const int* __restrict__ ei,
                                                 int* __restrict__ cursor, int* __restrict__ csr)
{
    int idx = blockIdx.x * 256 + threadIdx.x;
    if (idx >= ET) return;
    int s, d;
    if (idx < E0) { s = ei[idx]; d = ei[E0 + idx]; } else { s = d = idx - E0; }
    int pos = atomicAdd(&cursor[d], 1);
    csr[pos] = s;
}

// ---- Layer 1: h1 = x @ W1 (64x64) -> fp16, plus per-node a_dst logits ----
__global__ __launch_bounds__(256) void k_gemm1(
    const float* __restrict__ x, const float* __restrict__ W1,
    const float* __restrict__ ad1,
    __half* __restrict__ h1h, float* __restrict__ adst1)
{
    __shared__ float Wl[64 * 64];
    __shared__ float xs[4][64];
    int tid = threadIdx.x;
    for (int i = tid; i < 4096; i += 256) Wl[i] = W1[i];
    int w = tid >> 6, lane = tid & 63;
    int n = blockIdx.x * 4 + w;
    xs[w][lane] = x[n * 64 + lane];
    __syncthreads();
    float acc = 0.f;
#pragma unroll
    for (int k = 0; k < 64; ++k) acc += xs[w][k] * Wl[k * 64 + lane];
    h1h[n * 64 + lane] = __float2half(acc);
    int hh = lane >> 4, cc = lane & 15;
    float dv = acc * ad1[hh * 16 + cc];
#pragma unroll
    for (int off = 8; off; off >>= 1) dv += __shfl_down(dv, off, 16);
    if (cc == 0) adst1[n * 4 + hh] = dv;
}

// ---- Layer 1 aggregation: one wave per dst node. a_src recomputed in-register
// from the gathered h1 fragment (16-lane reduce) -> ONE random stream per edge.
// Unroll x4 for memory-level parallelism. Fused: bias, ELU, W2 proj -> g.
__global__ __launch_bounds__(256) void k_e1agg(
    const int* __restrict__ rowptr, const int* __restrict__ csr,
    const float* __restrict__ adst1, const __half* __restrict__ h1h,
    const float* __restrict__ as1, const float* __restrict__ b1,
    const float* __restrict__ W2, float* __restrict__ g)
{
    int w = threadIdx.x >> 6, lane = threadIdx.x & 63;
    int n = blockIdx.x * 4 + w;
    int hh = lane >> 4;
    float attv = as1[lane];          // att_src1[h][c], lane = h*16+c
    float ad = adst1[n * 4 + hh];
    int beg = rowptr[n], end = rowptr[n + 1];
    float acc = 0.f, den = 0.f;
    int j = beg;
    for (; j + 4 <= end; j += 4) {
        int s0 = csr[j], s1 = csr[j + 1], s2 = csr[j + 2], s3 = csr[j + 3];
        float h0 = __half2float(h1h[s0 * 64 + lane]);
        float h1v = __half2float(h1h[s1 * 64 + lane]);
        float h2 = __half2float(h1h[s2 * 64 + lane]);
        float h3 = __half2float(h1h[s3 * 64 + lane]);
        float p0 = h0 * attv, p1 = h1v * attv, p2 = h2 * attv, p3 = h3 * attv;
#pragma unroll
        for (int m = 8; m; m >>= 1) {
            p0 += __shfl_xor(p0, m, 16);
            p1 += __shfl_xor(p1, m, 16);
            p2 += __shfl_xor(p2, m, 16);
            p3 += __shfl_xor(p3, m, 16);
        }
        float a0 = p0 + ad; a0 = a0 > 0.f ? a0 : NEG * a0;
        float a1 = p1 + ad; a1 = a1 > 0.f ? a1 : NEG * a1;
        float a2 = p2 + ad; a2 = a2 > 0.f ? a2 : NEG * a2;
        float a3 = p3 + ad; a3 = a3 > 0.f ? a3 : NEG * a3;
        float e0 = __expf(a0), e1 = __expf(a1), e2 = __expf(a2), e3 = __expf(a3);
        den += (e0 + e1) + (e2 + e3);
        acc += e0 * h0 + e1 * h1v + e2 * h2 + e3 * h3;
    }
    for (; j < end; ++j) {
        int s = csr[j];
        float hv = __half2float(h1h[s * 64 + lane]);
        float p = hv * attv;
#pragma unroll
        for (int m = 8; m; m >>= 1) p += __shfl_xor(p, m, 16);
        float a = p + ad; a = a > 0.f ? a : NEG * a;
        float ev = __expf(a);
        den += ev;
        acc += ev * hv;
    }
    float v = acc / (den + EPSV) + b1[lane];
    v = v > 0.f ? v : expf(v) - 1.f;            // ELU
    float gv = v * W2[lane];
#pragma unroll
    for (int off = 32; off; off >>= 1) gv += __shfl_down(gv, off, 64);
    if (lane == 0) g[n] = gv;
}

// ---- Layer 2 aggregation: a_src2/a_dst2 are scalar multiples of g, so only
// ONE random gather (g[s]) per edge. One thread per dst node, unroll x8.
__global__ __launch_bounds__(256) void k_e2agg(
    const int* __restrict__ rowptr, const int* __restrict__ csr,
    const float* __restrict__ g, const float* __restrict__ att_s2,
    const float* __restrict__ att_d2, const float* __restrict__ b2,
    float* __restrict__ out)
{
    int n = blockIdx.x * 256 + threadIdx.x;
    if (n >= NN) return;
    float cs = att_s2[0];
    float gdcd = g[n] * att_d2[0];
    int beg = rowptr[n], end = rowptr[n + 1];
    float acc = 0.f, den = 0.f;
    int j = beg;
    for (; j + 8 <= end; j += 8) {
        int s0 = csr[j], s1 = csr[j+1], s2 = csr[j+2], s3 = csr[j+3];
        int s4 = csr[j+4], s5 = csr[j+5], s6 = csr[j+6], s7 = csr[j+7];
        float g0 = g[s0], g1 = g[s1], g2 = g[s2], g3 = g[s3];
        float g4 = g[s4], g5 = g[s5], g6 = g[s6], g7 = g[s7];
#define L2BODY(gz) { float a = gz * cs + gdcd; a = a > 0.f ? a : NEG * a; \
                     float ev = __expf(a); den += ev; acc += ev * gz; }
        L2BODY(g0) L2BODY(g1) L2BODY(g2) L2BODY(g3)
        L2BODY(g4) L2BODY(g5) L2BODY(g6) L2BODY(g7)
    }
    for (; j < end; ++j) {
        float gz = g[csr[j]];
        L2BODY(gz)
    }
#undef L2BODY
    out[n] = acc / (den + EPSV) + b2[0];
}

extern "C" void kernel_launch(void* const* d_in, const int* in_sizes, int n_in,
                              void* d_out, int out_size, void* d_ws, size_t ws_size,
                              hipStream_t stream)
{
    const float* x   = (const float*)d_in[0];
    const int*   ei  = (const int*)d_in[1];
    const float* W1  = (const float*)d_in[2];
    const float* as1 = (const float*)d_in[3];
    const float* ad1 = (const float*)d_in[4];
    const float* b1  = (const float*)d_in[5];
    const float* W2  = (const float*)d_in[6];
    const float* as2 = (const float*)d_in[7];
    const float* ad2 = (const float*)d_in[8];
    const float* b2  = (const float*)d_in[9];
    float* out = (float*)d_out;

    // workspace layout (units of 4 bytes from base)
    int*   iw     = (int*)d_ws;
    float* fw     = (float*)d_ws;
    int*   deg    = iw;                 // 100,000
    int*   rowptr = iw + 100000;        // 100,001
    int*   cursor = iw + 200008;        // 100,000
    int*   csr    = iw + 300008;        // 1,700,000
    int*   bsum   = iw + 2000008;       //       391
    int*   boff   = iw + 2000400;       //       391
    float* adst1  = fw + 2000800;       //   400,000
    float* g      = fw + 2400800;       //   100,000
    __half* h1h   = (__half*)(fw + 2500800); // 6.4M halves; byte off 10,003,200 (128B-aligned)
    // total ~5.7M slots ≈ 22.8 MB

    hipMemsetAsync(deg, 0, (size_t)NN * sizeof(int), stream);

    k_hist   <<<(ET + 255) / 256, 256, 0, stream>>>(ei, deg);
    k_s1     <<<NCHUNK, 256, 0, stream>>>(deg, bsum);
    k_s2     <<<1, 512, 0, stream>>>(bsum, boff);
    k_s3     <<<NCHUNK, 256, 0, stream>>>(deg, boff, rowptr, cursor);
    k_scatter<<<(ET + 255) / 256, 256, 0, stream>>>(ei, cursor, csr);
    k_gemm1  <<<NN / 4, 256, 0, stream>>>(x, W1, ad1, h1h, adst1);
    k_e1agg  <<<NN / 4, 256, 0, stream>>>(rowptr, csr, adst1, h1h, as1, b1, W2, g);
    k_e2agg  <<<(NN + 255) / 256, 256, 0, stream>>>(rowptr, csr, g, as2, ad2, b2, out);
}

// Round 5
// 329.857 us; speedup vs baseline: 2.7119x; 1.3556x over previous
//
#include <hip/hip_runtime.h>
#include <hip/hip_fp16.h>

#define NN   100000
#define E0   1600000
#define ET   1700000
#define NEG  0.2f
#define EPSV 1e-16f
#define NB   391            // dst buckets of 256 node ids (99999>>8 = 390)
#define BS   1024
#define NBLK ((ET + BS - 1) / BS)   // 1661

// ---- bucket counts: LDS-aggregated histogram over 391 dst buckets ----
__global__ __launch_bounds__(BS) void k_bcount(const int* __restrict__ ei, int* __restrict__ bcnt)
{
    __shared__ int cnt[NB];
    int t = threadIdx.x;
    if (t < NB) cnt[t] = 0;
    __syncthreads();
    int idx = blockIdx.x * BS + t;
    if (idx < ET) {
        int d = (idx < E0) ? ei[E0 + idx] : (idx - E0);
        atomicAdd(&cnt[d >> 8], 1);
    }
    __syncthreads();
    if (t < NB && cnt[t]) atomicAdd(&bcnt[t], cnt[t]);
}

// ---- exclusive scan of 391 bucket counts -> bbase, bcursor; rowptr sentinel ----
__global__ __launch_bounds__(512) void k_bscan(const int* __restrict__ bcnt,
                                               int* __restrict__ bbase, int* __restrict__ bcursor,
                                               int* __restrict__ rowptr)
{
    int t = threadIdx.x;
    int v = (t < NB) ? bcnt[t] : 0;
    int lane = t & 63, wid = t >> 6;
    int sc = v;
#pragma unroll
    for (int off = 1; off < 64; off <<= 1) {
        int u = __shfl_up(sc, off, 64);
        if (lane >= off) sc += u;
    }
    __shared__ int wsum[8];
    if (lane == 63) wsum[wid] = sc;
    __syncthreads();
    int woff = 0;
    for (int k = 0; k < wid; ++k) woff += wsum[k];
    if (t < NB) { int e = sc + woff - v; bbase[t] = e; bcursor[t] = e; }
    if (t == 0) rowptr[NN] = ET;
}

// ---- bin edges by dst bucket; packed record = s | (d&255)<<17 (s < 2^17) ----
__global__ __launch_bounds__(BS) void k_bscat(const int* __restrict__ ei,
                                              int* __restrict__ bcursor, int* __restrict__ bin)
{
    __shared__ int cnt[NB];
    __shared__ int base[NB];
    int t = threadIdx.x;
    if (t < NB) cnt[t] = 0;
    __syncthreads();
    int idx = blockIdx.x * BS + t;
    int b = 0, r = 0, pk = 0;
    if (idx < ET) {
        int s, d;
        if (idx < E0) { s = ei[idx]; d = ei[E0 + idx]; } else { s = d = idx - E0; }
        b = d >> 8;
        pk = s | ((d & 255) << 17);
        r = atomicAdd(&cnt[b], 1);
    }
    __syncthreads();
    if (t < NB && cnt[t]) base[t] = atomicAdd(&bcursor[t], cnt[t]);
    __syncthreads();
    if (idx < ET) bin[base[b] + r] = pk;
}

// ---- per-bucket CSR: local deg hist, local scan -> rowptr, local scatter -> csr.
// One block per bucket: all random accesses confined to one XCD's L2-hot window.
__global__ __launch_bounds__(256) void k_bcsr(const int* __restrict__ bin,
                                              const int* __restrict__ bbase, const int* __restrict__ bcnt,
                                              int* __restrict__ rowptr, int* __restrict__ csr)
{
    int b = blockIdx.x;
    int beg = bbase[b], cntB = bcnt[b];
    int t = threadIdx.x;
    __shared__ int deg[256];
    __shared__ int cur[256];
    deg[t] = 0;
    __syncthreads();
    for (int i = t; i < cntB; i += 256) atomicAdd(&deg[bin[beg + i] >> 17], 1);
    __syncthreads();
    int v = deg[t];
    int lane = t & 63, wid = t >> 6;
    int sc = v;
#pragma unroll
    for (int off = 1; off < 64; off <<= 1) {
        int u = __shfl_up(sc, off, 64);
        if (lane >= off) sc += u;
    }
    __shared__ int wsum[4];
    if (lane == 63) wsum[wid] = sc;
    __syncthreads();
    int woff = 0;
    for (int k = 0; k < wid; ++k) woff += wsum[k];
    int excl = sc - v + woff;
    cur[t] = excl;
    int node = (b << 8) + t;
    if (node < NN) rowptr[node] = beg + excl;
    __syncthreads();
    for (int i = t; i < cntB; i += 256) {
        int e = bin[beg + i];
        int r = atomicAdd(&cur[e >> 17], 1);
        csr[beg + r] = e & 0x1FFFF;
    }
}

// ---- Layer 1: h1 = x @ W1 (64x64) -> fp16, plus per-node a_dst logits ----
__global__ __launch_bounds__(256) void k_gemm1(
    const float* __restrict__ x, const float* __restrict__ W1,
    const float* __restrict__ ad1,
    __half* __restrict__ h1h, float* __restrict__ adst1)
{
    __shared__ float Wl[64 * 64];
    __shared__ float xs[4][64];
    int tid = threadIdx.x;
    for (int i = tid; i < 4096; i += 256) Wl[i] = W1[i];
    int w = tid >> 6, lane = tid & 63;
    int n = blockIdx.x * 4 + w;
    xs[w][lane] = x[n * 64 + lane];
    __syncthreads();
    float acc = 0.f;
#pragma unroll
    for (int k = 0; k < 64; ++k) acc += xs[w][k] * Wl[k * 64 + lane];
    h1h[n * 64 + lane] = __float2half(acc);
    int hh = lane >> 4, cc = lane & 15;
    float dv = acc * ad1[hh * 16 + cc];
#pragma unroll
    for (int off = 8; off; off >>= 1) dv += __shfl_down(dv, off, 16);
    if (cc == 0) adst1[n * 4 + hh] = dv;
}

// ---- Layer 1 aggregation: one wave per dst node; a_src recomputed in-register;
// unroll x4 for MLP. Fused: bias, ELU, W2 proj -> g. ----
__global__ __launch_bounds__(256) void k_e1agg(
    const int* __restrict__ rowptr, const int* __restrict__ csr,
    const float* __restrict__ adst1, const __half* __restrict__ h1h,
    const float* __restrict__ as1, const float* __restrict__ b1,
    const float* __restrict__ W2, float* __restrict__ g)
{
    int w = threadIdx.x >> 6, lane = threadIdx.x & 63;
    int n = blockIdx.x * 4 + w;
    int hh = lane >> 4;
    float attv = as1[lane];          // att_src1[h][c], lane = h*16+c
    float ad = adst1[n * 4 + hh];
    int beg = rowptr[n], end = rowptr[n + 1];
    float acc = 0.f, den = 0.f;
    int j = beg;
    for (; j + 4 <= end; j += 4) {
        int s0 = csr[j], s1 = csr[j + 1], s2 = csr[j + 2], s3 = csr[j + 3];
        float h0 = __half2float(h1h[s0 * 64 + lane]);
        float h1v = __half2float(h1h[s1 * 64 + lane]);
        float h2 = __half2float(h1h[s2 * 64 + lane]);
        float h3 = __half2float(h1h[s3 * 64 + lane]);
        float p0 = h0 * attv, p1 = h1v * attv, p2 = h2 * attv, p3 = h3 * attv;
#pragma unroll
        for (int m = 8; m; m >>= 1) {
            p0 += __shfl_xor(p0, m, 16);
            p1 += __shfl_xor(p1, m, 16);
            p2 += __shfl_xor(p2, m, 16);
            p3 += __shfl_xor(p3, m, 16);
        }
        float a0 = p0 + ad; a0 = a0 > 0.f ? a0 : NEG * a0;
        float a1 = p1 + ad; a1 = a1 > 0.f ? a1 : NEG * a1;
        float a2 = p2 + ad; a2 = a2 > 0.f ? a2 : NEG * a2;
        float a3 = p3 + ad; a3 = a3 > 0.f ? a3 : NEG * a3;
        float e0 = __expf(a0), e1 = __expf(a1), e2 = __expf(a2), e3 = __expf(a3);
        den += (e0 + e1) + (e2 + e3);
        acc += e0 * h0 + e1 * h1v + e2 * h2 + e3 * h3;
    }
    for (; j < end; ++j) {
        int s = csr[j];
        float hv = __half2float(h1h[s * 64 + lane]);
        float p = hv * attv;
#pragma unroll
        for (int m = 8; m; m >>= 1) p += __shfl_xor(p, m, 16);
        float a = p + ad; a = a > 0.f ? a : NEG * a;
        float ev = __expf(a);
        den += ev;
        acc += ev * hv;
    }
    float v = acc / (den + EPSV) + b1[lane];
    v = v > 0.f ? v : expf(v) - 1.f;            // ELU
    float gv = v * W2[lane];
#pragma unroll
    for (int off = 32; off; off >>= 1) gv += __shfl_down(gv, off, 64);
    if (lane == 0) g[n] = gv;
}

// ---- Layer 2 aggregation: one thread per dst node, one gather per edge ----
__global__ __launch_bounds__(256) void k_e2agg(
    const int* __restrict__ rowptr, const int* __restrict__ csr,
    const float* __restrict__ g, const float* __restrict__ att_s2,
    const float* __restrict__ att_d2, const float* __restrict__ b2,
    float* __restrict__ out)
{
    int n = blockIdx.x * 256 + threadIdx.x;
    if (n >= NN) return;
    float cs = att_s2[0];
    float gdcd = g[n] * att_d2[0];
    int beg = rowptr[n], end = rowptr[n + 1];
    float acc = 0.f, den = 0.f;
    int j = beg;
    for (; j + 8 <= end; j += 8) {
        int s0 = csr[j], s1 = csr[j+1], s2 = csr[j+2], s3 = csr[j+3];
        int s4 = csr[j+4], s5 = csr[j+5], s6 = csr[j+6], s7 = csr[j+7];
        float g0 = g[s0], g1 = g[s1], g2 = g[s2], g3 = g[s3];
        float g4 = g[s4], g5 = g[s5], g6 = g[s6], g7 = g[s7];
#define L2BODY(gz) { float a = gz * cs + gdcd; a = a > 0.f ? a : NEG * a; \
                     float ev = __expf(a); den += ev; acc += ev * gz; }
        L2BODY(g0) L2BODY(g1) L2BODY(g2) L2BODY(g3)
        L2BODY(g4) L2BODY(g5) L2BODY(g6) L2BODY(g7)
    }
    for (; j < end; ++j) {
        float gz = g[csr[j]];
        L2BODY(gz)
    }
#undef L2BODY
    out[n] = acc / (den + EPSV) + b2[0];
}

extern "C" void kernel_launch(void* const* d_in, const int* in_sizes, int n_in,
                              void* d_out, int out_size, void* d_ws, size_t ws_size,
                              hipStream_t stream)
{
    const float* x   = (const float*)d_in[0];
    const int*   ei  = (const int*)d_in[1];
    const float* W1  = (const float*)d_in[2];
    const float* as1 = (const float*)d_in[3];
    const float* ad1 = (const float*)d_in[4];
    const float* b1  = (const float*)d_in[5];
    const float* W2  = (const float*)d_in[6];
    const float* as2 = (const float*)d_in[7];
    const float* ad2 = (const float*)d_in[8];
    const float* b2  = (const float*)d_in[9];
    float* out = (float*)d_out;

    // workspace layout (4-byte units, 128-slot aligned blocks)
    int*   iw      = (int*)d_ws;
    float* fw      = (float*)d_ws;
    int*   bcnt    = iw;                  //      391
    int*   bbase   = iw + 512;            //      391
    int*   bcursor = iw + 1024;           //      391
    int*   rowptr  = iw + 1536;           //  100,001
    int*   bin     = iw + 101632;         // 1,700,000
    int*   csr     = iw + 1801728;        // 1,700,000
    float* adst1   = fw + 3501824;        //   400,000
    float* g       = fw + 3901952;        //   100,000
    __half* h1h    = (__half*)(fw + 4002048); // 6.4M halves
    // total ≈ 7.2M slots ≈ 28.8 MB

    hipMemsetAsync(bcnt, 0, NB * sizeof(int), stream);

    k_bcount<<<NBLK, BS, 0, stream>>>(ei, bcnt);
    k_bscan <<<1, 512, 0, stream>>>(bcnt, bbase, bcursor, rowptr);
    k_bscat <<<NBLK, BS, 0, stream>>>(ei, bcursor, bin);
    k_bcsr  <<<NB, 256, 0, stream>>>(bin, bbase, bcnt, rowptr, csr);
    k_gemm1 <<<NN / 4, 256, 0, stream>>>(x, W1, ad1, h1h, adst1);
    k_e1agg <<<NN / 4, 256, 0, stream>>>(rowptr, csr, adst1, h1h, as1, b1, W2, g);
    k_e2agg <<<(NN + 255) / 256, 256, 0, stream>>>(rowptr, csr, g, as2, ad2, b2, out);
}

// Round 6
// 307.723 us; speedup vs baseline: 2.9069x; 1.0719x over previous
//
#include <hip/hip_runtime.h>
#include <hip/hip_fp16.h>

#define NN   100000
#define E0   1600000
#define ET   1700000
#define NEG  0.2f
#define EPSV 1e-16f
#define NB   391            // dst buckets of 256 node ids
#define BS   1024
#define NBLK ((ET + BS - 1) / BS)   // 1661

// ---- bucket counts: LDS-aggregated histogram over 391 dst buckets ----
__global__ __launch_bounds__(BS) void k_bcount(const int* __restrict__ ei, int* __restrict__ bcnt)
{
    __shared__ int cnt[NB];
    int t = threadIdx.x;
    if (t < NB) cnt[t] = 0;
    __syncthreads();
    int idx = blockIdx.x * BS + t;
    if (idx < ET) {
        int d = (idx < E0) ? ei[E0 + idx] : (idx - E0);
        atomicAdd(&cnt[d >> 8], 1);
    }
    __syncthreads();
    if (t < NB && cnt[t]) atomicAdd(&bcnt[t], cnt[t]);
}

// ---- exclusive scan of 391 bucket counts -> bbase, bcursor; rowptr sentinel ----
__global__ __launch_bounds__(512) void k_bscan(const int* __restrict__ bcnt,
                                               int* __restrict__ bbase, int* __restrict__ bcursor,
                                               int* __restrict__ rowptr)
{
    int t = threadIdx.x;
    int v = (t < NB) ? bcnt[t] : 0;
    int lane = t & 63, wid = t >> 6;
    int sc = v;
#pragma unroll
    for (int off = 1; off < 64; off <<= 1) {
        int u = __shfl_up(sc, off, 64);
        if (lane >= off) sc += u;
    }
    __shared__ int wsum[8];
    if (lane == 63) wsum[wid] = sc;
    __syncthreads();
    int woff = 0;
    for (int k = 0; k < wid; ++k) woff += wsum[k];
    if (t < NB) { int e = sc + woff - v; bbase[t] = e; bcursor[t] = e; }
    if (t == 0) rowptr[NN] = ET;
}

// ---- bin edges by dst bucket; packed record = s | (d&255)<<17 (s < 2^17) ----
__global__ __launch_bounds__(BS) void k_bscat(const int* __restrict__ ei,
                                              int* __restrict__ bcursor, int* __restrict__ bin)
{
    __shared__ int cnt[NB];
    __shared__ int base[NB];
    int t = threadIdx.x;
    if (t < NB) cnt[t] = 0;
    __syncthreads();
    int idx = blockIdx.x * BS + t;
    int b = 0, r = 0, pk = 0;
    if (idx < ET) {
        int s, d;
        if (idx < E0) { s = ei[idx]; d = ei[E0 + idx]; } else { s = d = idx - E0; }
        b = d >> 8;
        pk = s | ((d & 255) << 17);
        r = atomicAdd(&cnt[b], 1);
    }
    __syncthreads();
    if (t < NB && cnt[t]) base[t] = atomicAdd(&bcursor[t], cnt[t]);
    __syncthreads();
    if (idx < ET) bin[base[b] + r] = pk;
}

// ---- per-bucket CSR: local deg hist, local scan -> rowptr, local scatter -> csr ----
__global__ __launch_bounds__(256) void k_bcsr(const int* __restrict__ bin,
                                              const int* __restrict__ bbase, const int* __restrict__ bcnt,
                                              int* __restrict__ rowptr, int* __restrict__ csr)
{
    int b = blockIdx.x;
    int beg = bbase[b], cntB = bcnt[b];
    int t = threadIdx.x;
    __shared__ int deg[256];
    __shared__ int cur[256];
    deg[t] = 0;
    __syncthreads();
    for (int i = t; i < cntB; i += 256) atomicAdd(&deg[bin[beg + i] >> 17], 1);
    __syncthreads();
    int v = deg[t];
    int lane = t & 63, wid = t >> 6;
    int sc = v;
#pragma unroll
    for (int off = 1; off < 64; off <<= 1) {
        int u = __shfl_up(sc, off, 64);
        if (lane >= off) sc += u;
    }
    __shared__ int wsum[4];
    if (lane == 63) wsum[wid] = sc;
    __syncthreads();
    int woff = 0;
    for (int k = 0; k < wid; ++k) woff += wsum[k];
    int excl = sc - v + woff;
    cur[t] = excl;
    int node = (b << 8) + t;
    if (node < NN) rowptr[node] = beg + excl;
    __syncthreads();
    for (int i = t; i < cntB; i += 256) {
        int e = bin[beg + i];
        int r = atomicAdd(&cur[e >> 17], 1);
        csr[beg + r] = e & 0x1FFFF;
    }
}

// ---- Layer 1: h1 = x @ W1 (64x64) -> fp16, plus per-node a_src/a_dst logits ----
__global__ __launch_bounds__(256) void k_gemm1(
    const float* __restrict__ x, const float* __restrict__ W1,
    const float* __restrict__ as1, const float* __restrict__ ad1,
    __half* __restrict__ h1h, float* __restrict__ asrc1, float* __restrict__ adst1)
{
    __shared__ float Wl[64 * 64];
    __shared__ float xs[4][64];
    int tid = threadIdx.x;
    for (int i = tid; i < 4096; i += 256) Wl[i] = W1[i];
    int w = tid >> 6, lane = tid & 63;
    int n = blockIdx.x * 4 + w;
    xs[w][lane] = x[n * 64 + lane];
    __syncthreads();
    float acc = 0.f;
#pragma unroll
    for (int k = 0; k < 64; ++k) acc += xs[w][k] * Wl[k * 64 + lane];
    h1h[n * 64 + lane] = __float2half(acc);
    int hh = lane >> 4, cc = lane & 15;
    float av = acc * as1[hh * 16 + cc];
    float dv = acc * ad1[hh * 16 + cc];
#pragma unroll
    for (int off = 8; off; off >>= 1) {
        av += __shfl_down(av, off, 16);
        dv += __shfl_down(dv, off, 16);
    }
    if (cc == 0) { asrc1[n * 4 + hh] = av; adst1[n * 4 + hh] = dv; }
}

// ---- Layer 1 aggregation: one wave per dst node, 4 edges/iteration,
// 16 lanes per edge, 4 channels per lane (half4 loads). a_src gathered
// (L2-resident). Fused epilogue: bias, ELU, W2 proj -> g. ----
__global__ __launch_bounds__(256) void k_e1agg(
    const int* __restrict__ rowptr, const int* __restrict__ csr,
    const float* __restrict__ asrc1, const float* __restrict__ adst1,
    const __half* __restrict__ h1h, const float* __restrict__ b1,
    const float* __restrict__ W2, float* __restrict__ g)
{
    int w = threadIdx.x >> 6, lane = threadIdx.x & 63;
    int n = blockIdx.x * 4 + w;
    int grp = lane >> 4;        // edge slot 0..3
    int cc  = lane & 15;        // channel quad: channels cc*4 .. cc*4+3
    int hh  = cc >> 2;          // head
    float ad = adst1[n * 4 + hh];
    int beg = rowptr[n], end = rowptr[n + 1];
    float a0 = 0.f, a1 = 0.f, a2 = 0.f, a3 = 0.f, den = 0.f;
    for (int j = beg; j < end; j += 4) {
        int jj = j + grp;
        int jc = jj < end ? jj : end - 1;       // clamp (deg>=1 via self-loop)
        int s = csr[jc];
        float as = asrc1[s * 4 + hh];
        float a = as + ad;
        a = a > 0.f ? a : NEG * a;
        float ev = __expf(a);
        if (jj >= end) ev = 0.f;
        uint2 u = *(const uint2*)(h1h + (size_t)s * 64 + cc * 4);
        float2 f01 = __half22float2(*(const __half2*)&u.x);
        float2 f23 = __half22float2(*(const __half2*)&u.y);
        den += ev;
        a0 += ev * f01.x; a1 += ev * f01.y;
        a2 += ev * f23.x; a3 += ev * f23.y;
    }
    // reduce across the 4 edge groups
#pragma unroll
    for (int m = 16; m <= 32; m <<= 1) {
        a0 += __shfl_xor(a0, m); a1 += __shfl_xor(a1, m);
        a2 += __shfl_xor(a2, m); a3 += __shfl_xor(a3, m);
        den += __shfl_xor(den, m);
    }
    // epilogue (all groups hold identical values; compute everywhere, write once)
    float inv = 1.f / (den + EPSV);
    const float4 bb = *(const float4*)(b1 + cc * 4);
    const float4 w2 = *(const float4*)(W2 + cc * 4);
    float v0 = a0 * inv + bb.x; v0 = v0 > 0.f ? v0 : expf(v0) - 1.f;
    float v1 = a1 * inv + bb.y; v1 = v1 > 0.f ? v1 : expf(v1) - 1.f;
    float v2 = a2 * inv + bb.z; v2 = v2 > 0.f ? v2 : expf(v2) - 1.f;
    float v3 = a3 * inv + bb.w; v3 = v3 > 0.f ? v3 : expf(v3) - 1.f;
    float gv = v0 * w2.x + v1 * w2.y + v2 * w2.z + v3 * w2.w;
#pragma unroll
    for (int m = 1; m <= 8; m <<= 1) gv += __shfl_xor(gv, m);
    if (lane == 0) g[n] = gv;
}

// ---- Layer 2 aggregation: 16 lanes per node, 16 edges in parallel ----
__global__ __launch_bounds__(256) void k_e2agg(
    const int* __restrict__ rowptr, const int* __restrict__ csr,
    const float* __restrict__ g, const float* __restrict__ att_s2,
    const float* __restrict__ att_d2, const float* __restrict__ b2,
    float* __restrict__ out)
{
    int t = threadIdx.x;
    int grp = t >> 4, cc = t & 15;
    int n = blockIdx.x * 16 + grp;     // NN/16 = 6250 exact
    float cs = att_s2[0];
    float gdcd = g[n] * att_d2[0];
    int beg = rowptr[n], end = rowptr[n + 1];
    float acc = 0.f, den = 0.f;
    for (int j = beg + cc; j < end; j += 16) {
        float gz = g[csr[j]];
        float a = gz * cs + gdcd;
        a = a > 0.f ? a : NEG * a;
        float ev = __expf(a);
        den += ev;
        acc += ev * gz;
    }
#pragma unroll
    for (int m = 1; m <= 8; m <<= 1) {
        acc += __shfl_xor(acc, m);
        den += __shfl_xor(den, m);
    }
    if (cc == 0) out[n] = acc / (den + EPSV) + b2[0];
}

extern "C" void kernel_launch(void* const* d_in, const int* in_sizes, int n_in,
                              void* d_out, int out_size, void* d_ws, size_t ws_size,
                              hipStream_t stream)
{
    const float* x   = (const float*)d_in[0];
    const int*   ei  = (const int*)d_in[1];
    const float* W1  = (const float*)d_in[2];
    const float* as1 = (const float*)d_in[3];
    const float* ad1 = (const float*)d_in[4];
    const float* b1  = (const float*)d_in[5];
    const float* W2  = (const float*)d_in[6];
    const float* as2 = (const float*)d_in[7];
    const float* ad2 = (const float*)d_in[8];
    const float* b2  = (const float*)d_in[9];
    float* out = (float*)d_out;

    // workspace layout (4-byte units, 128-slot aligned blocks)
    int*   iw      = (int*)d_ws;
    float* fw      = (float*)d_ws;
    int*   bcnt    = iw;                  //      391
    int*   bbase   = iw + 512;            //      391
    int*   bcursor = iw + 1024;           //      391
    int*   rowptr  = iw + 1536;           //  100,001
    int*   bin     = iw + 101632;         // 1,700,000
    int*   csr     = iw + 1801728;        // 1,700,000
    float* adst1   = fw + 3501824;        //   400,000
    float* asrc1   = fw + 3901952;        //   400,000
    float* g       = fw + 4302080;        //   100,000
    __half* h1h    = (__half*)(fw + 4402176); // 6.4M halves
    // total ≈ 7.6M slots ≈ 30.4 MB

    hipMemsetAsync(bcnt, 0, NB * sizeof(int), stream);

    k_bcount<<<NBLK, BS, 0, stream>>>(ei, bcnt);
    k_bscan <<<1, 512, 0, stream>>>(bcnt, bbase, bcursor, rowptr);
    k_bscat <<<NBLK, BS, 0, stream>>>(ei, bcursor, bin);
    k_bcsr  <<<NB, 256, 0, stream>>>(bin, bbase, bcnt, rowptr, csr);
    k_gemm1 <<<NN / 4, 256, 0, stream>>>(x, W1, as1, ad1, h1h, asrc1, adst1);
    k_e1agg <<<NN / 4, 256, 0, stream>>>(rowptr, csr, asrc1, adst1, h1h, b1, W2, g);
    k_e2agg <<<NN / 16, 256, 0, stream>>>(rowptr, csr, g, as2, ad2, b2, out);
}

// Round 7
// 285.682 us; speedup vs baseline: 3.1312x; 1.0772x over previous
//
#include <hip/hip_runtime.h>
#include <hip/hip_fp16.h>

#define NN   100000
#define E0   1600000
#define ET   1700000
#define NEG  0.2f
#define EPSV 1e-16f
#define NB   391            // dst buckets of 256 node ids
#define BS   1024
#define NBLK ((ET + BS - 1) / BS)   // 1661
#define GEMM_BLK 1024

// ---- bucket counts: LDS-aggregated histogram over 391 dst buckets ----
__global__ __launch_bounds__(BS) void k_bcount(const int* __restrict__ ei, int* __restrict__ bcnt)
{
    __shared__ int cnt[NB];
    int t = threadIdx.x;
    if (t < NB) cnt[t] = 0;
    __syncthreads();
    int idx = blockIdx.x * BS + t;
    if (idx < ET) {
        int d = (idx < E0) ? ei[E0 + idx] : (idx - E0);
        atomicAdd(&cnt[d >> 8], 1);
    }
    __syncthreads();
    if (t < NB && cnt[t]) atomicAdd(&bcnt[t], cnt[t]);
}

// ---- exclusive scan of 391 bucket counts -> bbase, bcursor; rowptr sentinel ----
__global__ __launch_bounds__(512) void k_bscan(const int* __restrict__ bcnt,
                                               int* __restrict__ bbase, int* __restrict__ bcursor,
                                               int* __restrict__ rowptr)
{
    int t = threadIdx.x;
    int v = (t < NB) ? bcnt[t] : 0;
    int lane = t & 63, wid = t >> 6;
    int sc = v;
#pragma unroll
    for (int off = 1; off < 64; off <<= 1) {
        int u = __shfl_up(sc, off, 64);
        if (lane >= off) sc += u;
    }
    __shared__ int wsum[8];
    if (lane == 63) wsum[wid] = sc;
    __syncthreads();
    int woff = 0;
    for (int k = 0; k < wid; ++k) woff += wsum[k];
    if (t < NB) { int e = sc + woff - v; bbase[t] = e; bcursor[t] = e; }
    if (t == 0) rowptr[NN] = ET;
}

// ---- bin edges by dst bucket; packed record = s | (d&255)<<17 (s < 2^17) ----
__global__ __launch_bounds__(BS) void k_bscat(const int* __restrict__ ei,
                                              int* __restrict__ bcursor, int* __restrict__ bin)
{
    __shared__ int cnt[NB];
    __shared__ int base[NB];
    int t = threadIdx.x;
    if (t < NB) cnt[t] = 0;
    __syncthreads();
    int idx = blockIdx.x * BS + t;
    int b = 0, r = 0, pk = 0;
    if (idx < ET) {
        int s, d;
        if (idx < E0) { s = ei[idx]; d = ei[E0 + idx]; } else { s = d = idx - E0; }
        b = d >> 8;
        pk = s | ((d & 255) << 17);
        r = atomicAdd(&cnt[b], 1);
    }
    __syncthreads();
    if (t < NB && cnt[t]) base[t] = atomicAdd(&bcursor[t], cnt[t]);
    __syncthreads();
    if (idx < ET) bin[base[b] + r] = pk;
}

// ---- per-bucket CSR: local deg hist, local scan -> rowptr, local scatter -> csr ----
__global__ __launch_bounds__(256) void k_bcsr(const int* __restrict__ bin,
                                              const int* __restrict__ bbase, const int* __restrict__ bcnt,
                                              int* __restrict__ rowptr, int* __restrict__ csr)
{
    int b = blockIdx.x;
    int beg = bbase[b], cntB = bcnt[b];
    int t = threadIdx.x;
    __shared__ int deg[256];
    __shared__ int cur[256];
    deg[t] = 0;
    __syncthreads();
    for (int i = t; i < cntB; i += 256) atomicAdd(&deg[bin[beg + i] >> 17], 1);
    __syncthreads();
    int v = deg[t];
    int lane = t & 63, wid = t >> 6;
    int sc = v;
#pragma unroll
    for (int off = 1; off < 64; off <<= 1) {
        int u = __shfl_up(sc, off, 64);
        if (lane >= off) sc += u;
    }
    __shared__ int wsum[4];
    if (lane == 63) wsum[wid] = sc;
    __syncthreads();
    int woff = 0;
    for (int k = 0; k < wid; ++k) woff += wsum[k];
    int excl = sc - v + woff;
    cur[t] = excl;
    int node = (b << 8) + t;
    if (node < NN) rowptr[node] = beg + excl;
    __syncthreads();
    for (int i = t; i < cntB; i += 256) {
        int e = bin[beg + i];
        int r = atomicAdd(&cur[e >> 17], 1);
        csr[beg + r] = e & 0x1FFFF;
    }
}

// ---- Layer 1 GEMM: W1 column in registers (per lane = output channel),
// x row via wave-uniform scalar loads; node-loop per wave. No LDS. ----
__global__ __launch_bounds__(256) void k_gemm1(
    const float* __restrict__ x, const float* __restrict__ W1,
    const float* __restrict__ as1, const float* __restrict__ ad1,
    __half* __restrict__ h1h, float* __restrict__ asrc1, float* __restrict__ adst1)
{
    int lane = threadIdx.x & 63;
    float wcol[64];
#pragma unroll
    for (int k = 0; k < 64; ++k) wcol[k] = W1[k * 64 + lane];
    float attS = as1[lane], attD = ad1[lane];
    int wid = (blockIdx.x * 256 + threadIdx.x) >> 6;
    const int nw = GEMM_BLK * 4;
    for (int n0 = wid; n0 < NN; n0 += nw) {
        int n = __builtin_amdgcn_readfirstlane(n0);
        const float4* xr = (const float4*)(x + (size_t)n * 64);
        float acc = 0.f;
#pragma unroll
        for (int m = 0; m < 16; ++m) {
            float4 xv = xr[m];
            acc += xv.x * wcol[4 * m] + xv.y * wcol[4 * m + 1]
                 + xv.z * wcol[4 * m + 2] + xv.w * wcol[4 * m + 3];
        }
        h1h[(size_t)n * 64 + lane] = __float2half(acc);
        float av = acc * attS, dv = acc * attD;
#pragma unroll
        for (int off = 8; off; off >>= 1) {
            av += __shfl_down(av, off, 16);
            dv += __shfl_down(dv, off, 16);
        }
        if ((lane & 15) == 0) {
            asrc1[n * 4 + (lane >> 4)] = av;
            adst1[n * 4 + (lane >> 4)] = dv;
        }
    }
}

// ---- Layer 1 aggregation: ONE THREAD PER NODE. 64 fp32 accs in registers,
// 8 x uint4 loads per gathered h1 row, per-head denominators, no cross-lane
// reduction. Epilogue (bias, ELU, W2 proj) fully in-register. ----
__global__ __launch_bounds__(128) void k_e1agg(
    const int* __restrict__ rowptr, const int* __restrict__ csr,
    const float* __restrict__ asrc1, const float* __restrict__ adst1,
    const __half* __restrict__ h1h, const float* __restrict__ b1,
    const float* __restrict__ W2, float* __restrict__ g)
{
    __shared__ float lb1[64], lw2[64];
    int t = threadIdx.x;
    if (t < 64) lb1[t] = b1[t];
    else lw2[t - 64] = W2[t - 64];
    __syncthreads();
    int n = blockIdx.x * 128 + t;
    if (n >= NN) return;
    float4 ad4 = *(const float4*)(adst1 + n * 4);
    int beg = rowptr[n], end = rowptr[n + 1];
    float acc[64];
#pragma unroll
    for (int c = 0; c < 64; ++c) acc[c] = 0.f;
    float den0 = 0.f, den1 = 0.f, den2 = 0.f, den3 = 0.f;
    for (int j = beg; j < end; ++j) {
        int s = csr[j];
        float4 as4 = *(const float4*)(asrc1 + s * 4);
        const uint4* hp = (const uint4*)(h1h + (size_t)s * 64);
        uint4 r0 = hp[0], r1 = hp[1], r2 = hp[2], r3 = hp[3];
        uint4 r4 = hp[4], r5 = hp[5], r6 = hp[6], r7 = hp[7];
        float a0 = as4.x + ad4.x; a0 = a0 > 0.f ? a0 : NEG * a0;
        float a1 = as4.y + ad4.y; a1 = a1 > 0.f ? a1 : NEG * a1;
        float a2 = as4.z + ad4.z; a2 = a2 > 0.f ? a2 : NEG * a2;
        float a3 = as4.w + ad4.w; a3 = a3 > 0.f ? a3 : NEG * a3;
        float e0 = __expf(a0), e1 = __expf(a1), e2 = __expf(a2), e3 = __expf(a3);
        den0 += e0; den1 += e1; den2 += e2; den3 += e3;
#define U4ACC(r, base, e) { \
        float2 f0 = __half22float2(*(const __half2*)&r.x); \
        float2 f1 = __half22float2(*(const __half2*)&r.y); \
        float2 f2 = __half22float2(*(const __half2*)&r.z); \
        float2 f3 = __half22float2(*(const __half2*)&r.w); \
        acc[base+0] += e * f0.x; acc[base+1] += e * f0.y; \
        acc[base+2] += e * f1.x; acc[base+3] += e * f1.y; \
        acc[base+4] += e * f2.x; acc[base+5] += e * f2.y; \
        acc[base+6] += e * f3.x; acc[base+7] += e * f3.y; }
        U4ACC(r0,  0, e0) U4ACC(r1,  8, e0)
        U4ACC(r2, 16, e1) U4ACC(r3, 24, e1)
        U4ACC(r4, 32, e2) U4ACC(r5, 40, e2)
        U4ACC(r6, 48, e3) U4ACC(r7, 56, e3)
#undef U4ACC
    }
    float inv0 = 1.f / (den0 + EPSV), inv1 = 1.f / (den1 + EPSV);
    float inv2 = 1.f / (den2 + EPSV), inv3 = 1.f / (den3 + EPSV);
    float gv = 0.f;
#pragma unroll
    for (int c = 0; c < 64; ++c) {
        float invc = (c < 16) ? inv0 : (c < 32) ? inv1 : (c < 48) ? inv2 : inv3;
        float v = acc[c] * invc + lb1[c];
        v = v > 0.f ? v : __expf(v) - 1.f;     // ELU
        gv += v * lw2[c];
    }
    g[n] = gv;
}

// ---- Layer 2 aggregation: 16 lanes per node, 16 edges in parallel ----
__global__ __launch_bounds__(256) void k_e2agg(
    const int* __restrict__ rowptr, const int* __restrict__ csr,
    const float* __restrict__ g, const float* __restrict__ att_s2,
    const float* __restrict__ att_d2, const float* __restrict__ b2,
    float* __restrict__ out)
{
    int t = threadIdx.x;
    int grp = t >> 4, cc = t & 15;
    int n = blockIdx.x * 16 + grp;     // NN/16 = 6250 exact
    float cs = att_s2[0];
    float gdcd = g[n] * att_d2[0];
    int beg = rowptr[n], end = rowptr[n + 1];
    float acc = 0.f, den = 0.f;
    for (int j = beg + cc; j < end; j += 16) {
        float gz = g[csr[j]];
        float a = gz * cs + gdcd;
        a = a > 0.f ? a : NEG * a;
        float ev = __expf(a);
        den += ev;
        acc += ev * gz;
    }
#pragma unroll
    for (int m = 1; m <= 8; m <<= 1) {
        acc += __shfl_xor(acc, m);
        den += __shfl_xor(den, m);
    }
    if (cc == 0) out[n] = acc / (den + EPSV) + b2[0];
}

extern "C" void kernel_launch(void* const* d_in, const int* in_sizes, int n_in,
                              void* d_out, int out_size, void* d_ws, size_t ws_size,
                              hipStream_t stream)
{
    const float* x   = (const float*)d_in[0];
    const int*   ei  = (const int*)d_in[1];
    const float* W1  = (const float*)d_in[2];
    const float* as1 = (const float*)d_in[3];
    const float* ad1 = (const float*)d_in[4];
    const float* b1  = (const float*)d_in[5];
    const float* W2  = (const float*)d_in[6];
    const float* as2 = (const float*)d_in[7];
    const float* ad2 = (const float*)d_in[8];
    const float* b2  = (const float*)d_in[9];
    float* out = (float*)d_out;

    // workspace layout (4-byte units, 128-slot aligned blocks)
    int*   iw      = (int*)d_ws;
    float* fw      = (float*)d_ws;
    int*   bcnt    = iw;                  //      391
    int*   bbase   = iw + 512;            //      391
    int*   bcursor = iw + 1024;           //      391
    int*   rowptr  = iw + 1536;           //  100,001
    int*   bin     = iw + 101632;         // 1,700,000
    int*   csr     = iw + 1801728;        // 1,700,000
    float* adst1   = fw + 3501824;        //   400,000
    float* asrc1   = fw + 3901952;        //   400,000
    float* g       = fw + 4302080;        //   100,000
    __half* h1h    = (__half*)(fw + 4402176); // 6.4M halves
    // total ≈ 7.6M slots ≈ 30.4 MB

    hipMemsetAsync(bcnt, 0, NB * sizeof(int), stream);

    k_bcount<<<NBLK, BS, 0, stream>>>(ei, bcnt);
    k_bscan <<<1, 512, 0, stream>>>(bcnt, bbase, bcursor, rowptr);
    k_bscat <<<NBLK, BS, 0, stream>>>(ei, bcursor, bin);
    k_bcsr  <<<NB, 256, 0, stream>>>(bin, bbase, bcnt, rowptr, csr);
    k_gemm1 <<<GEMM_BLK, 256, 0, stream>>>(x, W1, as1, ad1, h1h, asrc1, adst1);
    k_e1agg <<<(NN + 127) / 128, 128, 0, stream>>>(rowptr, csr, asrc1, adst1, h1h, b1, W2, g);
    k_e2agg <<<NN / 16, 256, 0, stream>>>(rowptr, csr, g, as2, ad2, b2, out);
}

// Round 8
// 269.618 us; speedup vs baseline: 3.3178x; 1.0596x over previous
//
#include <hip/hip_runtime.h>
#include <hip/hip_fp16.h>

#define NN   100000
#define E0   1600000
#define ET   1700000
#define NEG  0.2f
#define EPSV 1e-16f
#define NB   391            // dst buckets of 256 node ids
#define BS   1024
#define NBLK ((ET + BS - 1) / BS)   // 1661
#define GEMM_BLK 1024

// ---- bucket counts: LDS-aggregated histogram over 391 dst buckets ----
__global__ __launch_bounds__(BS) void k_bcount(const int* __restrict__ ei, int* __restrict__ bcnt)
{
    __shared__ int cnt[NB];
    int t = threadIdx.x;
    if (t < NB) cnt[t] = 0;
    __syncthreads();
    int idx = blockIdx.x * BS + t;
    if (idx < ET) {
        int d = (idx < E0) ? ei[E0 + idx] : (idx - E0);
        atomicAdd(&cnt[d >> 8], 1);
    }
    __syncthreads();
    if (t < NB && cnt[t]) atomicAdd(&bcnt[t], cnt[t]);
}

// ---- exclusive scan of 391 bucket counts -> bbase, bcursor; rowptr sentinel ----
__global__ __launch_bounds__(512) void k_bscan(const int* __restrict__ bcnt,
                                               int* __restrict__ bbase, int* __restrict__ bcursor,
                                               int* __restrict__ rowptr)
{
    int t = threadIdx.x;
    int v = (t < NB) ? bcnt[t] : 0;
    int lane = t & 63, wid = t >> 6;
    int sc = v;
#pragma unroll
    for (int off = 1; off < 64; off <<= 1) {
        int u = __shfl_up(sc, off, 64);
        if (lane >= off) sc += u;
    }
    __shared__ int wsum[8];
    if (lane == 63) wsum[wid] = sc;
    __syncthreads();
    int woff = 0;
    for (int k = 0; k < wid; ++k) woff += wsum[k];
    if (t < NB) { int e = sc + woff - v; bbase[t] = e; bcursor[t] = e; }
    if (t == 0) rowptr[NN] = ET;
}

// ---- bin edges by dst bucket; packed record = s | (d&255)<<17 (s < 2^17) ----
__global__ __launch_bounds__(BS) void k_bscat(const int* __restrict__ ei,
                                              int* __restrict__ bcursor, int* __restrict__ bin)
{
    __shared__ int cnt[NB];
    __shared__ int base[NB];
    int t = threadIdx.x;
    if (t < NB) cnt[t] = 0;
    __syncthreads();
    int idx = blockIdx.x * BS + t;
    int b = 0, r = 0, pk = 0;
    if (idx < ET) {
        int s, d;
        if (idx < E0) { s = ei[idx]; d = ei[E0 + idx]; } else { s = d = idx - E0; }
        b = d >> 8;
        pk = s | ((d & 255) << 17);
        r = atomicAdd(&cnt[b], 1);
    }
    __syncthreads();
    if (t < NB && cnt[t]) base[t] = atomicAdd(&bcursor[t], cnt[t]);
    __syncthreads();
    if (idx < ET) bin[base[b] + r] = pk;
}

// ---- per-bucket CSR: local deg hist, local scan -> rowptr, local scatter -> csr ----
__global__ __launch_bounds__(256) void k_bcsr(const int* __restrict__ bin,
                                              const int* __restrict__ bbase, const int* __restrict__ bcnt,
                                              int* __restrict__ rowptr, int* __restrict__ csr)
{
    int b = blockIdx.x;
    int beg = bbase[b], cntB = bcnt[b];
    int t = threadIdx.x;
    __shared__ int deg[256];
    __shared__ int cur[256];
    deg[t] = 0;
    __syncthreads();
    for (int i = t; i < cntB; i += 256) atomicAdd(&deg[bin[beg + i] >> 17], 1);
    __syncthreads();
    int v = deg[t];
    int lane = t & 63, wid = t >> 6;
    int sc = v;
#pragma unroll
    for (int off = 1; off < 64; off <<= 1) {
        int u = __shfl_up(sc, off, 64);
        if (lane >= off) sc += u;
    }
    __shared__ int wsum[4];
    if (lane == 63) wsum[wid] = sc;
    __syncthreads();
    int woff = 0;
    for (int k = 0; k < wid; ++k) woff += wsum[k];
    int excl = sc - v + woff;
    cur[t] = excl;
    int node = (b << 8) + t;
    if (node < NN) rowptr[node] = beg + excl;
    __syncthreads();
    for (int i = t; i < cntB; i += 256) {
        int e = bin[beg + i];
        int r = atomicAdd(&cur[e >> 17], 1);
        csr[beg + r] = e & 0x1FFFF;
    }
}

// ---- Layer 1 GEMM: W1 column in registers (per lane = output channel),
// x row via wave-uniform scalar loads; node-loop per wave. No LDS. ----
__global__ __launch_bounds__(256) void k_gemm1(
    const float* __restrict__ x, const float* __restrict__ W1,
    const float* __restrict__ as1, const float* __restrict__ ad1,
    __half* __restrict__ h1h, float* __restrict__ asrc1, float* __restrict__ adst1)
{
    int lane = threadIdx.x & 63;
    float wcol[64];
#pragma unroll
    for (int k = 0; k < 64; ++k) wcol[k] = W1[k * 64 + lane];
    float attS = as1[lane], attD = ad1[lane];
    int wid = (blockIdx.x * 256 + threadIdx.x) >> 6;
    const int nw = GEMM_BLK * 4;
    for (int n0 = wid; n0 < NN; n0 += nw) {
        int n = __builtin_amdgcn_readfirstlane(n0);
        const float4* xr = (const float4*)(x + (size_t)n * 64);
        float acc = 0.f;
#pragma unroll
        for (int m = 0; m < 16; ++m) {
            float4 xv = xr[m];
            acc += xv.x * wcol[4 * m] + xv.y * wcol[4 * m + 1]
                 + xv.z * wcol[4 * m + 2] + xv.w * wcol[4 * m + 3];
        }
        h1h[(size_t)n * 64 + lane] = __float2half(acc);
        float av = acc * attS, dv = acc * attD;
#pragma unroll
        for (int off = 8; off; off >>= 1) {
            av += __shfl_down(av, off, 16);
            dv += __shfl_down(dv, off, 16);
        }
        if ((lane & 15) == 0) {
            asrc1[n * 4 + (lane >> 4)] = av;
            adst1[n * 4 + (lane >> 4)] = dv;
        }
    }
}

// ---- Layer 1 aggregation: 4 LANES PER NODE (lane = head). Each lane owns
// its head's 16 channels (16 fp32 accs), loads 32B of each gathered h1 row,
// own exp/denominator. Epilogue in-register; 2-step shfl_xor combine. ----
__global__ __launch_bounds__(256) void k_e1agg(
    const int* __restrict__ rowptr, const int* __restrict__ csr,
    const float* __restrict__ asrc1, const float* __restrict__ adst1,
    const __half* __restrict__ h1h, const float* __restrict__ b1,
    const float* __restrict__ W2, float* __restrict__ g)
{
    int t = threadIdx.x;
    int hh = t & 3;                 // head
    int n = blockIdx.x * 64 + (t >> 2);
    if (n >= NN) return;
    float ad = adst1[n * 4 + hh];
    int beg = rowptr[n], end = rowptr[n + 1];
    float acc[16];
#pragma unroll
    for (int c = 0; c < 16; ++c) acc[c] = 0.f;
    float den = 0.f;
    for (int j = beg; j < end; ++j) {
        int s = csr[j];
        float as = asrc1[s * 4 + hh];
        float a = as + ad; a = a > 0.f ? a : NEG * a;
        float ev = __expf(a);
        den += ev;
        const uint4* hp = (const uint4*)(h1h + (size_t)s * 64 + hh * 16);
        uint4 r0 = hp[0], r1 = hp[1];
#define U4ACC(r, base) { \
        float2 f0 = __half22float2(*(const __half2*)&r.x); \
        float2 f1 = __half22float2(*(const __half2*)&r.y); \
        float2 f2 = __half22float2(*(const __half2*)&r.z); \
        float2 f3 = __half22float2(*(const __half2*)&r.w); \
        acc[base+0] += ev * f0.x; acc[base+1] += ev * f0.y; \
        acc[base+2] += ev * f1.x; acc[base+3] += ev * f1.y; \
        acc[base+4] += ev * f2.x; acc[base+5] += ev * f2.y; \
        acc[base+6] += ev * f3.x; acc[base+7] += ev * f3.y; }
        U4ACC(r0, 0) U4ACC(r1, 8)
#undef U4ACC
    }
    float inv = 1.f / (den + EPSV);
    const float4* bp = (const float4*)(b1 + hh * 16);
    const float4* wp = (const float4*)(W2 + hh * 16);
    float gv = 0.f;
#pragma unroll
    for (int q = 0; q < 4; ++q) {
        float4 bb = bp[q], w2 = wp[q];
        float v0 = acc[4*q+0] * inv + bb.x; v0 = v0 > 0.f ? v0 : __expf(v0) - 1.f;
        float v1 = acc[4*q+1] * inv + bb.y; v1 = v1 > 0.f ? v1 : __expf(v1) - 1.f;
        float v2 = acc[4*q+2] * inv + bb.z; v2 = v2 > 0.f ? v2 : __expf(v2) - 1.f;
        float v3 = acc[4*q+3] * inv + bb.w; v3 = v3 > 0.f ? v3 : __expf(v3) - 1.f;
        gv += v0 * w2.x + v1 * w2.y + v2 * w2.z + v3 * w2.w;
    }
    gv += __shfl_xor(gv, 1);
    gv += __shfl_xor(gv, 2);
    if (hh == 0) g[n] = gv;
}

// ---- Layer 2 aggregation: 16 lanes per node, 16 edges in parallel ----
__global__ __launch_bounds__(256) void k_e2agg(
    const int* __restrict__ rowptr, const int* __restrict__ csr,
    const float* __restrict__ g, const float* __restrict__ att_s2,
    const float* __restrict__ att_d2, const float* __restrict__ b2,
    float* __restrict__ out)
{
    int t = threadIdx.x;
    int grp = t >> 4, cc = t & 15;
    int n = blockIdx.x * 16 + grp;     // NN/16 = 6250 exact
    float cs = att_s2[0];
    float gdcd = g[n] * att_d2[0];
    int beg = rowptr[n], end = rowptr[n + 1];
    float acc = 0.f, den = 0.f;
    for (int j = beg + cc; j < end; j += 16) {
        float gz = g[csr[j]];
        float a = gz * cs + gdcd;
        a = a > 0.f ? a : NEG * a;
        float ev = __expf(a);
        den += ev;
        acc += ev * gz;
    }
#pragma unroll
    for (int m = 1; m <= 8; m <<= 1) {
        acc += __shfl_xor(acc, m);
        den += __shfl_xor(den, m);
    }
    if (cc == 0) out[n] = acc / (den + EPSV) + b2[0];
}

extern "C" void kernel_launch(void* const* d_in, const int* in_sizes, int n_in,
                              void* d_out, int out_size, void* d_ws, size_t ws_size,
                              hipStream_t stream)
{
    const float* x   = (const float*)d_in[0];
    const int*   ei  = (const int*)d_in[1];
    const float* W1  = (const float*)d_in[2];
    const float* as1 = (const float*)d_in[3];
    const float* ad1 = (const float*)d_in[4];
    const float* b1  = (const float*)d_in[5];
    const float* W2  = (const float*)d_in[6];
    const float* as2 = (const float*)d_in[7];
    const float* ad2 = (const float*)d_in[8];
    const float* b2  = (const float*)d_in[9];
    float* out = (float*)d_out;

    // workspace layout (4-byte units, 128-slot aligned blocks)
    int*   iw      = (int*)d_ws;
    float* fw      = (float*)d_ws;
    int*   bcnt    = iw;                  //      391
    int*   bbase   = iw + 512;            //      391
    int*   bcursor = iw + 1024;           //      391
    int*   rowptr  = iw + 1536;           //  100,001
    int*   bin     = iw + 101632;         // 1,700,000
    int*   csr     = iw + 1801728;        // 1,700,000
    float* adst1   = fw + 3501824;        //   400,000
    float* asrc1   = fw + 3901952;        //   400,000
    float* g       = fw + 4302080;        //   100,000
    __half* h1h    = (__half*)(fw + 4402176); // 6.4M halves
    // total ≈ 7.6M slots ≈ 30.4 MB

    hipMemsetAsync(bcnt, 0, NB * sizeof(int), stream);

    k_bcount<<<NBLK, BS, 0, stream>>>(ei, bcnt);
    k_bscan <<<1, 512, 0, stream>>>(bcnt, bbase, bcursor, rowptr);
    k_bscat <<<NBLK, BS, 0, stream>>>(ei, bcursor, bin);
    k_bcsr  <<<NB, 256, 0, stream>>>(bin, bbase, bcnt, rowptr, csr);
    k_gemm1 <<<GEMM_BLK, 256, 0, stream>>>(x, W1, as1, ad1, h1h, asrc1, adst1);
    k_e1agg <<<(NN * 4 + 255) / 256, 256, 0, stream>>>(rowptr, csr, asrc1, adst1, h1h, b1, W2, g);
    k_e2agg <<<NN / 16, 256, 0, stream>>>(rowptr, csr, g, as2, ad2, b2, out);
}